// Round 8
// baseline (758.510 us; speedup 1.0000x reference)
//
#include <hip/hip_runtime.h>
#include <hip/hip_bf16.h>
#include <hip/hip_fp16.h>

#define N 1024
#define D 128
#define SB 32          // steps per superstep (gi chunk staged in LDS)
#define NSB (N / SB)

typedef __hip_bfloat16 bf16;
typedef __attribute__((ext_vector_type(4))) float fx4;
typedef __attribute__((ext_vector_type(8))) unsigned short u16x8;

__device__ __forceinline__ float b2f(bf16 x) { return __bfloat162float(x); }
__device__ __forceinline__ unsigned short f2bf_bits(float x) {
    bf16 b = __float2bfloat16(x);
    return *reinterpret_cast<unsigned short*>(&b);
}
__device__ __forceinline__ float bfbits2f(unsigned short u) {
    return __uint_as_float(((unsigned int)u) << 16);
}
__device__ __forceinline__ float fastrcp(float x) { return __builtin_amdgcn_rcpf(x); }

__device__ __forceinline__ float fast_tanh(float x) {
    float e = __expf(2.f * x);
    return 1.f - 2.f * fastrcp(e + 1.f);
}
__device__ __forceinline__ float fast_sigmoid(float x) {
    return fastrcp(1.f + __expf(-x));
}

// guaranteed packed f16 FMA: acc.{lo,hi} += a.{lo,hi} * b.{lo,hi}
__device__ __forceinline__ void pkfma(unsigned int& acc, unsigned int a, unsigned int b) {
    asm("v_pk_fma_f16 %0, %1, %2, %0" : "+v"(acc) : "v"(a), "v"(b));
}
__device__ __forceinline__ unsigned int pack_h2(float a, float b) {
    __half2 h = __floats2half2_rn(a, b);
    return *reinterpret_cast<unsigned int*>(&h);
}
__device__ __forceinline__ float h2_sumf(unsigned int u) {
    __half2 h = *reinterpret_cast<__half2*>(&u);
    return __low2float(h) + __high2float(h);
}

// async 16B global->LDS
__device__ __forceinline__ void async_copy16(const float* g, void* l) {
    __builtin_amdgcn_global_load_lds((const __attribute__((address_space(1))) void*)g,
                                     (__attribute__((address_space(3))) void*)l, 16, 0, 0);
}

// ---------------- K0a: dtype sniff ----------------
__global__ void sniff_kernel(const unsigned short* __restrict__ xu, int* __restrict__ flag) {
    int l = threadIdx.x;  // 64 threads
    int cnt = 0;
#pragma unroll
    for (int k = 0; k < 8; ++k) {
        unsigned short u = xu[2 * (l * 8 + k)];
        int e = (u >> 7) & 0xFF;
        cnt += (e >= 96 && e <= 144) ? 1 : 0;
    }
    for (int off = 32; off > 0; off >>= 1) cnt += __shfl_down(cnt, off);
    if (l == 0) *flag = (cnt > 400) ? 1 : 0;
}

// ---------------- K0b: convert all inputs to fp32 in ws ----------------
struct ConvArgs {
    const void* p[8];
    float* o[8];
    int n[8];
};
__global__ void convert_kernel(ConvArgs A, const int* __restrict__ flag) {
    int seg = blockIdx.y;
    int n = A.n[seg];
    int isbf = *flag;
    const void* p = A.p[seg];
    float* o = A.o[seg];
    for (int i = blockIdx.x * blockDim.x + threadIdx.x; i < n; i += gridDim.x * blockDim.x) {
        float v = isbf ? b2f(((const bf16*)p)[i]) : ((const float*)p)[i];
        o[i] = v;
    }
}

// ---------------- K0c: w_ihT[c][o] = w_ih[o][c] ----------------
__global__ void transpose_wih(const float* __restrict__ wih, float* __restrict__ wihT) {
    int id = blockIdx.x * 256 + threadIdx.x;   // 98304 total
    int c = id / 384;
    int o = id - c * 384;
    wihT[id] = wih[o * 256 + c];
}

// ---------------- K1: q = X@Wq^T, kT = (X@Wk^T)^T ----------------
__global__ void qk_kernel(const float* __restrict__ X, const float* __restrict__ Wq,
                          const float* __restrict__ Wk,
                          float* __restrict__ q, float* __restrict__ kT) {
    int i = blockIdx.x & (N - 1);
    bool is_k = blockIdx.x >= N;
    int d = threadIdx.x;  // 0..127
    const float* W = is_k ? Wk : Wq;
    float acc = 0.f;
#pragma unroll 8
    for (int c = 0; c < D; ++c)
        acc += X[i * D + c] * W[d * D + c];
    if (is_k) kT[d * N + i] = acc;
    else      q[i * D + d] = acc;
}

// ---------------- K2: fused scores+softmax+att+gi per row i ----------------
__global__ void __launch_bounds__(256) attn_kernel(const float* __restrict__ q,
                                                   const float* __restrict__ kT,
                                                   const float* __restrict__ v,
                                                   const float* __restrict__ X,
                                                   const float* __restrict__ wihT,
                                                   const float* __restrict__ b_ih,
                                                   float* __restrict__ gi) {
    int i = blockIdx.x;
    __shared__ float qs[D], vs[D], xr[D], al[D];
    __shared__ float wrow[N];
    __shared__ float red[256];
    int t = threadIdx.x;
    if (t < D) { qs[t] = q[i * D + t]; vs[t] = v[t]; xr[t] = X[i * D + t]; }
    __syncthreads();

    float sj[4];
    int cnt = 0;
    float m = -1e30f;
    for (int j = i + t; j < N; j += 256) {
        float s = 0.f;
#pragma unroll 8
        for (int d = 0; d < D; ++d) s += vs[d] * fast_tanh(qs[d] + kT[d * N + j]);
        sj[cnt++] = s;
        m = fmaxf(m, s);
    }
    red[t] = m;
    __syncthreads();
    for (int st = 128; st > 0; st >>= 1) {
        if (t < st) red[t] = fmaxf(red[t], red[t + st]);
        __syncthreads();
    }
    m = red[0];
    __syncthreads();
    float lsum = 0.f;
    {
        int it = 0;
        for (int j = i + t; j < N; j += 256, ++it) {
            float p = __expf(sj[it] - m);
            wrow[j] = p;
            lsum += p;
        }
    }
    red[t] = lsum;
    __syncthreads();
    for (int st = 128; st > 0; st >>= 1) {
        if (t < st) red[t] += red[t + st];
        __syncthreads();
    }
    float inv = fastrcp(red[0]);
    __syncthreads();

    int d = t & 127, half = t >> 7;
    float acc = 0.f;
    for (int j = i + half; j < N; j += 2) acc += wrow[j] * X[j * D + d];
    if (half) red[d] = acc;
    __syncthreads();
    if (!half) al[d] = (acc + red[d]) * inv;
    __syncthreads();

    for (int o = t; o < 3 * D; o += 256) {
        float a2 = b_ih[o];
        const float* wt = wihT + o;
#pragma unroll 8
        for (int c = 0; c < D; ++c) a2 += xr[c] * wt[c * 384];
#pragma unroll 8
        for (int c = 0; c < D; ++c) a2 += al[c] * wt[(D + c) * 384];
        gi[i * 3 * D + o] = a2;
    }
}

// ---------------- K3: sequential GRU via v_pk_fma_f16 (inline asm), 4 waves ----
// Thread t: dim d = t>>1, k-half = t&1. Weight rows {d, d+128, d+256} x 64-k as
// 96 packed-f16 VGPRs. Per step: 8 ds_read_b128 of h (2-addr broadcast, free),
// 96 v_pk_fma_f16 (6 chains), widen 3 gate accs, 3 shfl_xor(1), f32 gates,
// f16 h ping-pong + bf16 obuf, one lgkm-only barrier. gi for step s+1 is
// prefetched into regs BEFORE step s's barrier (latency hidden across it).
// R7's fdot2 scalarized to ~576 VALU cyc/step — asm guarantees the packed op.
__global__ void __launch_bounds__(256, 1) gru_kernel(const float* __restrict__ gi,
                                                     const float* __restrict__ w_hh,
                                                     const float* __restrict__ b_hh,
                                                     void* __restrict__ out,
                                                     const int* __restrict__ flag) {
    __shared__ float gi_lds[2][SB][3 * D];     // 2 x 48 KB
    __shared__ unsigned int hcur[2][D / 2];    // h ping-pong, f16 packed, 256 B each
    __shared__ unsigned short obuf[SB][D];     // bf16 output staging, 8 KB
    int t = threadIdx.x;
    int d = t >> 1;
    int half = t & 1;
    int isbf = *flag;

    // --- weights rows d, d+128, d+256, k in [64*half, 64*half+64), packed f16 ---
    unsigned int wr[32], wz[32], wn[32];
    {
        const float* wb = w_hh + 64 * half;
#pragma unroll
        for (int j = 0; j < 32; ++j) {
            wr[j] = pack_h2(wb[d * D + 2 * j], wb[d * D + 2 * j + 1]);
            wz[j] = pack_h2(wb[(d + D) * D + 2 * j], wb[(d + D) * D + 2 * j + 1]);
            wn[j] = pack_h2(wb[(d + 2 * D) * D + 2 * j], wb[(d + 2 * D) * D + 2 * j + 1]);
        }
    }
    float br = b_hh[d], bz = b_hh[D + d], bn = b_hh[2 * D + d];
    float h = 0.f;

    int fr = t >> 3;            // obuf flush: row fr, 16 cols at fc
    int fc = (t & 7) * 16;

    // prefetch superstep 0
    {
        for (int mm = 0; mm < 12; ++mm) {
            int off = ((t >> 6) * 12 + mm) * 256;
            async_copy16(gi + off + ((t & 63) << 2), (char*)&gi_lds[0][0][0] + off * 4);
        }
    }

    for (int sb = 0; sb < NSB; ++sb) {
        int cb = sb & 1;
        if (sb == 0) {
            if (t < 64) ((int*)&hcur[0][0])[t] = 0;
        } else {
            u16x8 h0 = *(const u16x8*)&obuf[fr][fc];
            u16x8 h1 = *(const u16x8*)&obuf[fr][fc + 8];
            int orow = (sb - 1) * SB + fr;
            if (isbf) {
                *(u16x8*)((unsigned short*)out + orow * D + fc) = h0;
                *(u16x8*)((unsigned short*)out + orow * D + fc + 8) = h1;
            } else {
                float* op = (float*)out + orow * D + fc;
                fx4 f0, f1, f2, f3;
#pragma unroll
                for (int j = 0; j < 4; ++j) {
                    f0[j] = bfbits2f(h0[j]);     f1[j] = bfbits2f(h0[4 + j]);
                    f2[j] = bfbits2f(h1[j]);     f3[j] = bfbits2f(h1[4 + j]);
                }
                *(fx4*)op = f0; *(fx4*)(op + 4) = f1;
                *(fx4*)(op + 8) = f2; *(fx4*)(op + 12) = f3;
            }
        }
        asm volatile("s_waitcnt vmcnt(0) lgkmcnt(0)\ns_barrier" ::: "memory");

        if (sb + 1 < NSB) {
            const float* src = gi + (size_t)(sb + 1) * SB * 3 * D;
            for (int mm = 0; mm < 12; ++mm) {
                int off = ((t >> 6) * 12 + mm) * 256;
                async_copy16(src + off + ((t & 63) << 2), (char*)&gi_lds[cb ^ 1][0][0] + off * 4);
            }
        }

        const float* gp = &gi_lds[cb][0][0] + d;
        float gr = gp[0], gz = gp[D], gn = gp[2 * D];   // step-0 gi

        for (int s = 0; s < SB; ++s) {
            int pp = s & 1;
            // h chunk: 64 f16 = 128 B as 8 b128 reads (2-address broadcast)
            union { fx4 v4[8]; unsigned int u[32]; } hu;
            {
                const fx4* hp4 = (const fx4*)&hcur[pp][half * 32];
#pragma unroll
                for (int j = 0; j < 8; ++j) hu.v4[j] = hp4[j];
            }

            unsigned int ar0 = 0, ar1 = 0, az0 = 0, az1 = 0, an0 = 0, an1 = 0;
#pragma unroll
            for (int j = 0; j < 16; ++j) {
                pkfma(ar0, wr[j], hu.u[j]);
                pkfma(ar1, wr[j + 16], hu.u[j + 16]);
                pkfma(az0, wz[j], hu.u[j]);
                pkfma(az1, wz[j + 16], hu.u[j + 16]);
                pkfma(an0, wn[j], hu.u[j]);
                pkfma(an1, wn[j + 16], hu.u[j + 16]);
            }
            float sr = h2_sumf(ar0) + h2_sumf(ar1);
            float sz = h2_sumf(az0) + h2_sumf(az1);
            float sn = h2_sumf(an0) + h2_sumf(an1);
            sr += __shfl_xor(sr, 1);
            sz += __shfl_xor(sz, 1);
            sn += __shfl_xor(sn, 1);

            float rr = fast_sigmoid(gr + sr + br);
            float zz = fast_sigmoid(gz + sz + bz);
            float nst = fast_tanh(gn + rr * (sn + bn));
            h = (1.f - zz) * nst + zz * h;

            if (!half) {
                __half hh = __float2half(h);
                ((unsigned short*)&hcur[pp ^ 1][0])[d] = *reinterpret_cast<unsigned short*>(&hh);
                obuf[s][d] = f2bf_bits(h);
            }
            // prefetch next step's gi BEFORE the barrier (hides ds latency)
            if (s + 1 < SB) {
                gp += 3 * D;
                gr = gp[0]; gz = gp[D]; gn = gp[2 * D];
            }
            asm volatile("s_waitcnt lgkmcnt(0)\ns_barrier" ::: "memory");
        }
    }
    // final flush
    {
        u16x8 h0 = *(const u16x8*)&obuf[fr][fc];
        u16x8 h1 = *(const u16x8*)&obuf[fr][fc + 8];
        int orow = (NSB - 1) * SB + fr;
        if (isbf) {
            *(u16x8*)((unsigned short*)out + orow * D + fc) = h0;
            *(u16x8*)((unsigned short*)out + orow * D + fc + 8) = h1;
        } else {
            float* op = (float*)out + orow * D + fc;
            fx4 f0, f1, f2, f3;
#pragma unroll
            for (int j = 0; j < 4; ++j) {
                f0[j] = bfbits2f(h0[j]);     f1[j] = bfbits2f(h0[4 + j]);
                f2[j] = bfbits2f(h1[j]);     f3[j] = bfbits2f(h1[4 + j]);
            }
            *(fx4*)op = f0; *(fx4*)(op + 4) = f1;
            *(fx4*)(op + 8) = f2; *(fx4*)(op + 12) = f3;
        }
    }
}

extern "C" void kernel_launch(void* const* d_in, const int* in_sizes, int n_in,
                              void* d_out, int out_size, void* d_ws, size_t ws_size,
                              hipStream_t stream) {
    (void)in_sizes; (void)n_in; (void)out_size; (void)ws_size;

    float* w0 = (float*)d_ws;
    int*   flag = (int*)w0;
    float* Xf   = w0 + 16;
    float* Wqf  = Xf   + N * D;
    float* Wkf  = Wqf  + D * D;
    float* vf   = Wkf  + D * D;
    float* wihf = vf   + D;
    float* whhf = wihf + 3 * D * 2 * D;
    float* bihf = whhf + 3 * D * D;
    float* bhhf = bihf + 3 * D;
    float* q    = bhhf + 3 * D;
    float* kT   = q    + N * D;
    float* wihT = kT   + N * D;
    float* gi   = wihT + 3 * D * 2 * D;

    sniff_kernel<<<1, 64, 0, stream>>>((const unsigned short*)d_in[0], flag);

    ConvArgs A;
    A.p[0] = d_in[0]; A.o[0] = Xf;   A.n[0] = N * D;
    A.p[1] = d_in[1]; A.o[1] = Wqf;  A.n[1] = D * D;
    A.p[2] = d_in[2]; A.o[2] = Wkf;  A.n[2] = D * D;
    A.p[3] = d_in[3]; A.o[3] = vf;   A.n[3] = D;
    A.p[4] = d_in[4]; A.o[4] = wihf; A.n[4] = 3 * D * 2 * D;
    A.p[5] = d_in[5]; A.o[5] = whhf; A.n[5] = 3 * D * D;
    A.p[6] = d_in[6]; A.o[6] = bihf; A.n[6] = 3 * D;
    A.p[7] = d_in[7]; A.o[7] = bhhf; A.n[7] = 3 * D;
    dim3 cgrid(128, 8, 1);
    convert_kernel<<<cgrid, 256, 0, stream>>>(A, flag);

    transpose_wih<<<(3 * D * 2 * D) / 256, 256, 0, stream>>>(wihf, wihT);
    qk_kernel<<<2 * N, D, 0, stream>>>(Xf, Wqf, Wkf, q, kT);
    attn_kernel<<<N, 256, 0, stream>>>(q, kT, vf, Xf, wihT, bihf, gi);
    gru_kernel<<<1, 256, 0, stream>>>(gi, whhf, bhhf, d_out, flag);
}

// Round 9
// 714.693 us; speedup vs baseline: 1.0613x; 1.0613x over previous
//
#include <hip/hip_runtime.h>
#include <hip/hip_bf16.h>

#define N 1024
#define D 128
#define SB 32          // steps per superstep (gi chunk staged in LDS)
#define NSB (N / SB)

typedef __hip_bfloat16 bf16;
typedef __attribute__((ext_vector_type(8))) short bfx8;    // 8 bf16 MFMA A/B frag
typedef __attribute__((ext_vector_type(4))) float fx4;     // MFMA C/D frag
typedef __attribute__((ext_vector_type(8))) unsigned short u16x8;

__device__ __forceinline__ float b2f(bf16 x) { return __bfloat162float(x); }
__device__ __forceinline__ short f2bf_bits(float x) {
    bf16 b = __float2bfloat16(x);
    return *reinterpret_cast<short*>(&b);
}
__device__ __forceinline__ float bfbits2f(unsigned short u) {
    return __uint_as_float(((unsigned int)u) << 16);
}
__device__ __forceinline__ float fastrcp(float x) { return __builtin_amdgcn_rcpf(x); }

__device__ __forceinline__ float fast_tanh(float x) {
    float e = __expf(2.f * x);
    return 1.f - 2.f * fastrcp(e + 1.f);
}
__device__ __forceinline__ float fast_sigmoid(float x) {
    return fastrcp(1.f + __expf(-x));
}

__device__ __forceinline__ float sel4(fx4 v, int r) {
    float x = (r & 1) ? v[1] : v[0];
    float y = (r & 1) ? v[3] : v[2];
    return (r & 2) ? y : x;
}

__device__ __forceinline__ void async_copy16(const float* g, void* l) {
    __builtin_amdgcn_global_load_lds((const __attribute__((address_space(1))) void*)g,
                                     (__attribute__((address_space(3))) void*)l, 16, 0, 0);
}

// ---------------- K0a: dtype sniff ----------------
__global__ void sniff_kernel(const unsigned short* __restrict__ xu, int* __restrict__ flag) {
    int l = threadIdx.x;  // 64 threads
    int cnt = 0;
#pragma unroll
    for (int k = 0; k < 8; ++k) {
        unsigned short u = xu[2 * (l * 8 + k)];
        int e = (u >> 7) & 0xFF;
        cnt += (e >= 96 && e <= 144) ? 1 : 0;
    }
    for (int off = 32; off > 0; off >>= 1) cnt += __shfl_down(cnt, off);
    if (l == 0) *flag = (cnt > 400) ? 1 : 0;
}

// ---------------- K0b: convert all inputs to fp32 in ws ----------------
struct ConvArgs {
    const void* p[8];
    float* o[8];
    int n[8];
};
__global__ void convert_kernel(ConvArgs A, const int* __restrict__ flag) {
    int seg = blockIdx.y;
    int n = A.n[seg];
    int isbf = *flag;
    const void* p = A.p[seg];
    float* o = A.o[seg];
    for (int i = blockIdx.x * blockDim.x + threadIdx.x; i < n; i += gridDim.x * blockDim.x) {
        float v = isbf ? b2f(((const bf16*)p)[i]) : ((const float*)p)[i];
        o[i] = v;
    }
}

// ---------------- K0c: w_ihT[c][o] = w_ih[o][c] ----------------
__global__ void transpose_wih(const float* __restrict__ wih, float* __restrict__ wihT) {
    int id = blockIdx.x * 256 + threadIdx.x;   // 98304 total
    int c = id / 384;
    int o = id - c * 384;
    wihT[id] = wih[o * 256 + c];
}

// ---------------- K1: q = X@Wq^T, kT = (X@Wk^T)^T ----------------
__global__ void qk_kernel(const float* __restrict__ X, const float* __restrict__ Wq,
                          const float* __restrict__ Wk,
                          float* __restrict__ q, float* __restrict__ kT) {
    int i = blockIdx.x & (N - 1);
    bool is_k = blockIdx.x >= N;
    int d = threadIdx.x;  // 0..127
    const float* W = is_k ? Wk : Wq;
    float acc = 0.f;
#pragma unroll 8
    for (int c = 0; c < D; ++c)
        acc += X[i * D + c] * W[d * D + c];
    if (is_k) kT[d * N + i] = acc;
    else      q[i * D + d] = acc;
}

// ================= mega kernel: block 0 = GRU consumer, blocks 1..N = attn producers =================
#define SMEM_BYTES 106752   // max(gru: 98304+8448, attn: 7168)

__device__ __forceinline__ void wait_chunk(const int* rflag, int base, int t) {
    if (t < SB) {
        while (__hip_atomic_load(rflag + base + t, __ATOMIC_ACQUIRE,
                                 __HIP_MEMORY_SCOPE_AGENT) == 0) {
            __builtin_amdgcn_s_sleep(1);
        }
    }
    __syncthreads();
}

// ---- attention producer for row i: scores+softmax+att+gi, then release rflag[i] ----
__device__ void attn_body(char* smem, int i,
                          const float* __restrict__ q, const float* __restrict__ kT,
                          const float* __restrict__ v, const float* __restrict__ X,
                          const float* __restrict__ wihT, const float* __restrict__ b_ih,
                          float* __restrict__ gi, int* __restrict__ rflag) {
    float* qs = (float*)smem;      // D
    float* vs = qs + D;            // D
    float* xr = vs + D;            // D
    float* al = xr + D;            // D
    float* wrow = al + D;          // N
    float* red = wrow + N;         // 256
    int t = threadIdx.x;
    if (t < D) { qs[t] = q[i * D + t]; vs[t] = v[t]; xr[t] = X[i * D + t]; }
    __syncthreads();

    float sj[4];
    int cnt = 0;
    float m = -1e30f;
    for (int j = i + t; j < N; j += 256) {
        float s = 0.f;
#pragma unroll 8
        for (int d = 0; d < D; ++d) s += vs[d] * fast_tanh(qs[d] + kT[d * N + j]);
        sj[cnt++] = s;
        m = fmaxf(m, s);
    }
    red[t] = m;
    __syncthreads();
    for (int st = 128; st > 0; st >>= 1) {
        if (t < st) red[t] = fmaxf(red[t], red[t + st]);
        __syncthreads();
    }
    m = red[0];
    __syncthreads();
    float lsum = 0.f;
    {
        int it = 0;
        for (int j = i + t; j < N; j += 256, ++it) {
            float p = __expf(sj[it] - m);
            wrow[j] = p;
            lsum += p;
        }
    }
    red[t] = lsum;
    __syncthreads();
    for (int st = 128; st > 0; st >>= 1) {
        if (t < st) red[t] += red[t + st];
        __syncthreads();
    }
    float inv = fastrcp(red[0]);
    __syncthreads();

    int d = t & 127, half = t >> 7;
    float acc = 0.f;
    for (int j = i + half; j < N; j += 2) acc += wrow[j] * X[j * D + d];
    if (half) red[d] = acc;
    __syncthreads();
    if (!half) al[d] = (acc + red[d]) * inv;
    __syncthreads();

    for (int o = t; o < 3 * D; o += 256) {
        float a2 = b_ih[o];
        const float* wt = wihT + o;
#pragma unroll 8
        for (int c = 0; c < D; ++c) a2 += xr[c] * wt[c * 384];
#pragma unroll 8
        for (int c = 0; c < D; ++c) a2 += al[c] * wt[(D + c) * 384];
        gi[i * 3 * D + o] = a2;
    }
    __threadfence();          // make gi row visible device-wide
    __syncthreads();
    if (t == 0) __hip_atomic_store(rflag + i, 1, __ATOMIC_RELEASE, __HIP_MEMORY_SCOPE_AGENT);
}

// ---- GRU consumer: the R6 448us MFMA kernel + per-chunk flag waits ----
__device__ void gru_body(char* smem, const float* __restrict__ gi,
                         const float* __restrict__ w_hh, const float* __restrict__ b_hh,
                         void* __restrict__ out, const int* __restrict__ dflag,
                         const int* __restrict__ rflag) {
    float (*gi_lds)[SB][3 * D] = (float (*)[SB][3 * D])smem;    // 2 x 48 KB
    short (*hist)[D] = (short (*)[D])(smem + 98304);            // [SB+1][D]
    int t = threadIdx.x;
    int w = t >> 6;
    int l = t & 63;
    int q = l >> 4;
    int nn = l & 15;
    int isbf = *dflag;

    // A-frags: a[tau][mqi][kc]; A[m=nn][k=32kc+8q+j]
    bfx8 a[3][2][4];
#pragma unroll
    for (int tau = 0; tau < 3; ++tau)
#pragma unroll
        for (int mqi = 0; mqi < 2; ++mqi)
#pragma unroll
            for (int kc = 0; kc < 4; ++kc) {
                int row = 128 * tau + 16 * (2 * w + mqi) + nn;
                int k0 = 32 * kc + 8 * q;
#pragma unroll
                for (int j = 0; j < 8; ++j)
                    a[tau][mqi][kc][j] = f2bf_bits(w_hh[row * D + k0 + j]);
            }
    fx4 bias[3][2];
#pragma unroll
    for (int tau = 0; tau < 3; ++tau)
#pragma unroll
        for (int mqi = 0; mqi < 2; ++mqi)
#pragma unroll
            for (int r = 0; r < 4; ++r)
                bias[tau][mqi][r] = b_hh[128 * tau + 16 * (2 * w + mqi) + 4 * q + r];

    int rsel = l & 3;
    int mqsel = (l >> 3) & 1;
    int drow = 32 * w + 16 * mqsel + 4 * q + rsel;
    float h = 0.f;

    int fr = 1 + (t >> 3);
    int fc = (t & 7) * 16;

    // wait for rows 0..31, then prefetch superstep 0
    wait_chunk(rflag, 0, t);
    {
        for (int mm = 0; mm < 12; ++mm) {
            int off = (w * 12 + mm) * 256;
            async_copy16(gi + off + (l << 2), (char*)&gi_lds[0][0][0] + off * 4);
        }
    }

    for (int sb = 0; sb < NSB; ++sb) {
        int cb = sb & 1;
        if (sb == 0) {
            if (t < 64) ((int*)&hist[0][0])[t] = 0;
        } else {
            u16x8 h0 = *(const u16x8*)&hist[fr][fc];
            u16x8 h1 = *(const u16x8*)&hist[fr][fc + 8];
            int orow = (sb - 1) * SB + fr - 1;
            if (isbf) {
                *(u16x8*)((unsigned short*)out + orow * D + fc) = h0;
                *(u16x8*)((unsigned short*)out + orow * D + fc + 8) = h1;
            } else {
                float* op = (float*)out + orow * D + fc;
                fx4 f0, f1, f2, f3;
#pragma unroll
                for (int j = 0; j < 4; ++j) {
                    f0[j] = bfbits2f(h0[j]);     f1[j] = bfbits2f(h0[4 + j]);
                    f2[j] = bfbits2f(h1[j]);     f3[j] = bfbits2f(h1[4 + j]);
                }
                *(fx4*)op = f0; *(fx4*)(op + 4) = f1;
                *(fx4*)(op + 8) = f2; *(fx4*)(op + 12) = f3;
            }
            if (t < 64) ((int*)&hist[0][0])[t] = ((const int*)&hist[SB][0])[t];
        }
        asm volatile("s_waitcnt vmcnt(0) lgkmcnt(0)\ns_barrier" ::: "memory");

        if (sb + 1 < NSB) {
            wait_chunk(rflag, (sb + 1) * SB, t);   // producers must be done
            const float* src = gi + (size_t)(sb + 1) * SB * 3 * D;
            for (int mm = 0; mm < 12; ++mm) {
                int off = (w * 12 + mm) * 256;
                async_copy16(src + off + (l << 2), (char*)&gi_lds[cb ^ 1][0][0] + off * 4);
            }
        }

        const char* hrd = (const char*)&hist[0][0] + 16 * q;
        const float* gp = &gi_lds[cb][0][0] + drow;
        short* hwr = &hist[1][0] + drow;

        for (int s = 0; s < SB; ++s) {
            bfx8 b0 = *(const bfx8*)(hrd);
            bfx8 b1 = *(const bfx8*)(hrd + 64);
            bfx8 b2 = *(const bfx8*)(hrd + 128);
            bfx8 b3 = *(const bfx8*)(hrd + 192);
            float gr = gp[0];
            float gz = gp[D];
            float gn = gp[2 * D];

            fx4 acc[3][2];
#pragma unroll
            for (int tau = 0; tau < 3; ++tau)
#pragma unroll
                for (int mqi = 0; mqi < 2; ++mqi) {
                    fx4 c = bias[tau][mqi];
                    c = __builtin_amdgcn_mfma_f32_16x16x32_bf16(a[tau][mqi][0], b0, c, 0, 0, 0);
                    c = __builtin_amdgcn_mfma_f32_16x16x32_bf16(a[tau][mqi][1], b1, c, 0, 0, 0);
                    c = __builtin_amdgcn_mfma_f32_16x16x32_bf16(a[tau][mqi][2], b2, c, 0, 0, 0);
                    c = __builtin_amdgcn_mfma_f32_16x16x32_bf16(a[tau][mqi][3], b3, c, 0, 0, 0);
                    acc[tau][mqi] = c;
                }

            float ar = sel4(mqsel ? acc[0][1] : acc[0][0], rsel);
            float az = sel4(mqsel ? acc[1][1] : acc[1][0], rsel);
            float an = sel4(mqsel ? acc[2][1] : acc[2][0], rsel);
            float rr = fast_sigmoid(gr + ar);
            float zz = fast_sigmoid(gz + az);
            float nst = fast_tanh(gn + rr * an);
            h = (1.f - zz) * nst + zz * h;
            *hwr = f2bf_bits(h);     // 2 replica lanes, same addr+data: free

            hrd += 256;
            gp += 3 * D;
            hwr += D;
            asm volatile("s_waitcnt lgkmcnt(0)\ns_barrier" ::: "memory");
        }
    }
    // final flush
    {
        u16x8 h0 = *(const u16x8*)&hist[fr][fc];
        u16x8 h1 = *(const u16x8*)&hist[fr][fc + 8];
        int orow = (NSB - 1) * SB + fr - 1;
        if (isbf) {
            *(u16x8*)((unsigned short*)out + orow * D + fc) = h0;
            *(u16x8*)((unsigned short*)out + orow * D + fc + 8) = h1;
        } else {
            float* op = (float*)out + orow * D + fc;
            fx4 f0, f1, f2, f3;
#pragma unroll
            for (int j = 0; j < 4; ++j) {
                f0[j] = bfbits2f(h0[j]);     f1[j] = bfbits2f(h0[4 + j]);
                f2[j] = bfbits2f(h1[j]);     f3[j] = bfbits2f(h1[4 + j]);
            }
            *(fx4*)op = f0; *(fx4*)(op + 4) = f1;
            *(fx4*)(op + 8) = f2; *(fx4*)(op + 12) = f3;
        }
    }
}

__global__ void __launch_bounds__(256, 1) mega_kernel(const float* __restrict__ q,
                                                      const float* __restrict__ kT,
                                                      const float* __restrict__ v,
                                                      const float* __restrict__ X,
                                                      const float* __restrict__ wihT,
                                                      const float* __restrict__ b_ih,
                                                      float* __restrict__ gi,
                                                      const float* __restrict__ w_hh,
                                                      const float* __restrict__ b_hh,
                                                      void* __restrict__ out,
                                                      const int* __restrict__ dflag,
                                                      int* __restrict__ rflag) {
    __shared__ __align__(16) char smem[SMEM_BYTES];
    if (blockIdx.x != 0) {
        attn_body(smem, (int)blockIdx.x - 1, q, kT, v, X, wihT, b_ih, gi, rflag);
    } else {
        gru_body(smem, gi, w_hh, b_hh, out, dflag, rflag);
    }
}

extern "C" void kernel_launch(void* const* d_in, const int* in_sizes, int n_in,
                              void* d_out, int out_size, void* d_ws, size_t ws_size,
                              hipStream_t stream) {
    (void)in_sizes; (void)n_in; (void)out_size; (void)ws_size;

    float* w0 = (float*)d_ws;
    int*   dflag = (int*)w0;                  // [0..15] dtype flag + pad
    int*   rflag = (int*)(w0 + 16);           // N row-ready flags
    float* Xf   = w0 + 16 + N;                // fp32 staging begins
    float* Wqf  = Xf   + N * D;
    float* Wkf  = Wqf  + D * D;
    float* vf   = Wkf  + D * D;
    float* wihf = vf   + D;
    float* whhf = wihf + 3 * D * 2 * D;
    float* bihf = whhf + 3 * D * D;
    float* bhhf = bihf + 3 * D;
    float* q    = bhhf + 3 * D;
    float* kT   = q    + N * D;
    float* wihT = kT   + N * D;
    float* gi   = wihT + 3 * D * 2 * D;

    sniff_kernel<<<1, 64, 0, stream>>>((const unsigned short*)d_in[0], dflag);
    hipMemsetAsync(rflag, 0, N * sizeof(int), stream);   // ws is poisoned 0xAA

    ConvArgs A;
    A.p[0] = d_in[0]; A.o[0] = Xf;   A.n[0] = N * D;
    A.p[1] = d_in[1]; A.o[1] = Wqf;  A.n[1] = D * D;
    A.p[2] = d_in[2]; A.o[2] = Wkf;  A.n[2] = D * D;
    A.p[3] = d_in[3]; A.o[3] = vf;   A.n[3] = D;
    A.p[4] = d_in[4]; A.o[4] = wihf; A.n[4] = 3 * D * 2 * D;
    A.p[5] = d_in[5]; A.o[5] = whhf; A.n[5] = 3 * D * D;
    A.p[6] = d_in[6]; A.o[6] = bihf; A.n[6] = 3 * D;
    A.p[7] = d_in[7]; A.o[7] = bhhf; A.n[7] = 3 * D;
    dim3 cgrid(128, 8, 1);
    convert_kernel<<<cgrid, 256, 0, stream>>>(A, dflag);

    transpose_wih<<<(3 * D * 2 * D) / 256, 256, 0, stream>>>(wihf, wihT);
    qk_kernel<<<2 * N, D, 0, stream>>>(Xf, Wqf, Wkf, q, kT);
    mega_kernel<<<1 + N, 256, 0, stream>>>(q, kT, vf, Xf, wihT, bihf, gi,
                                           whhf, bhhf, d_out, dflag, rflag);
}